// Round 3
// baseline (4309.557 us; speedup 1.0000x reference)
//
#include <hip/hip_runtime.h>
#include <hip/hip_bf16.h>

typedef unsigned short u16;
typedef unsigned int u32;
typedef unsigned long long u64;
typedef __attribute__((ext_vector_type(8))) short bf16x8;   // 8 bf16 in 4 VGPRs
typedef __attribute__((ext_vector_type(4))) float f32x4;    // MFMA acc
typedef __attribute__((ext_vector_type(4))) unsigned int u32x4;

#define MFMA16(a, b, c) __builtin_amdgcn_mfma_f32_16x16x32_bf16((a), (b), (c), 0, 0, 0)

static constexpr int Ee = 300, EP = 320, Hh = 1024, G3 = 3072;
static constexpr int Bb = 64, Tt = 512;

// workspace layout (bytes)
static constexpr long OFF_GX   = 0L;                      // [512][3072][64] bf16 = 201326592
static constexpr long OFF_EMB  = 201326592L;              // [32768][320] bf16   = 20971520
static constexpr long OFF_WIH  = 222298112L;              // [3072][320] bf16    = 1966080
static constexpr long OFF_WHH  = 224264192L;              // [3072][1024] bf16   = 6291456
static constexpr long OFF_HBUF = 230555648L;              // 4 grp x 2 slot x [16][1024] u32 tagged

__device__ __forceinline__ u16 f2bf(float f) {
    union { float f; unsigned u; } v; v.f = f;
    unsigned u = v.u;
    return (u16)((u + 0x7fffu + ((u >> 16) & 1u)) >> 16);   // RNE
}
__device__ __forceinline__ float bf2f(u16 u) {
    union { unsigned u; float f; } v; v.u = ((unsigned)u) << 16;
    return v.f;
}
__device__ __forceinline__ float fast_sigmoid(float x) {
    return 1.f / (1.f + __expf(-x));
}
__device__ __forceinline__ float fast_tanh(float x) {
    float ax = fabsf(x);
    float e = __expf(-2.f * ax);
    float t = (1.f - e) / (1.f + e);
    return copysignf(t, x);
}

// ---------------------------------------------------------------- prep ------
static constexpr long R0 = (long)Bb * Tt * EP;   // emb gather (bf16, padded)
static constexpr long R1 = (long)G3 * EP;        // W_ih -> bf16 padded
static constexpr long R2 = (long)G3 * Hh;        // W_hh -> bf16
static constexpr long R3 = 131072;               // tagged h words: slot0 = (0|tag0), slot1 = sentinel
static constexpr long R5 = 320;                  // out = bias (d_out is poisoned!)

__global__ void prep_kernel(const int* __restrict__ x, const float* __restrict__ emb,
                            const float* __restrict__ wih, const float* __restrict__ whh,
                            const float* __restrict__ bfc,
                            u16* __restrict__ emb_bf, u16* __restrict__ wih_bf,
                            u16* __restrict__ whh_bf, u32* __restrict__ h32,
                            float* __restrict__ out) {
    const long total = R0 + R1 + R2 + R3 + R5;
    for (long i = (long)blockIdx.x * blockDim.x + threadIdx.x; i < total;
         i += (long)gridDim.x * blockDim.x) {
        if (i < R0) {
            const int m = (int)(i / EP), k = (int)(i % EP);
            const int b = m & 63, t = m >> 6;
            u16 v = 0;
            if (k < Ee) {
                const int xi = x[b * Tt + t];
                v = f2bf(emb[(size_t)xi * Ee + k]);
            }
            emb_bf[i] = v;
        } else if (i < R0 + R1) {
            const long j = i - R0;
            const int k = (int)(j % EP);
            const int n = (int)(j / EP);
            wih_bf[j] = (k < Ee) ? f2bf(wih[(size_t)n * Ee + k]) : (u16)0;
        } else if (i < R0 + R1 + R2) {
            const long j = i - R0 - R1;
            whh_bf[j] = f2bf(whh[j]);
        } else if (i < R0 + R1 + R2 + R3) {
            const long j = i - R0 - R1 - R2;
            // per group: slot0 (16384 words) = payload 0 / tag 0 == h_0; slot1 = tag 0xFFFF
            h32[j] = ((j >> 14) & 1) ? 0xFFFFu : 0u;
        } else {
            const long j = i - R0 - R1 - R2 - R3;
            out[j] = bfc[j % 5];
        }
    }
}

// ------------------------------------------------------------- gx GEMM ------
// gx[t][n][b] = sum_k emb_bf[m=t*64+b][k] * wih_bf[n][k] + b_ih[n], bf16 out.
__global__ __launch_bounds__(256, 2)
void gx_gemm(const u16* __restrict__ A, const u16* __restrict__ Bm,
             const float* __restrict__ bih, u16* __restrict__ gx) {
    __shared__ __align__(16) u16 lA[128 * 32];
    __shared__ __align__(16) u16 lB[128 * 32];
    const int tid = threadIdx.x;
    const int lane = tid & 63;
    const int wv = tid >> 6;
    const int quad = lane >> 4, l15 = lane & 15;
    const int m0 = blockIdx.x * 128;
    const int n0 = blockIdx.y * 128;
    const int mo = (wv & 1) * 64, no = (wv >> 1) * 64;
    const int srow = tid >> 2;
    const int sseg = tid & 3;

    f32x4 acc[4][4] = {};

    for (int s = 0; s < 10; ++s) {
        const int k0 = s * 32;
        __syncthreads();
#pragma unroll
        for (int p = 0; p < 2; ++p) {
            const u16* ga = A + (size_t)(m0 + p * 64 + srow) * EP + k0 + sseg * 8;
            u16* la = &lA[p * 2048 + wv * 512];
            __builtin_amdgcn_global_load_lds(
                (const __attribute__((address_space(1))) void*)ga,
                (__attribute__((address_space(3))) void*)la, 16, 0, 0);
            const u16* gb = Bm + (size_t)(n0 + p * 64 + srow) * EP + k0 + sseg * 8;
            u16* lb = &lB[p * 2048 + wv * 512];
            __builtin_amdgcn_global_load_lds(
                (const __attribute__((address_space(1))) void*)gb,
                (__attribute__((address_space(3))) void*)lb, 16, 0, 0);
        }
        __syncthreads();

        bf16x8 af[4], bfr[4];
#pragma unroll
        for (int mt = 0; mt < 4; ++mt)
            af[mt] = *(const bf16x8*)&lA[(mo + mt * 16 + l15) * 32 + quad * 8];
#pragma unroll
        for (int nt = 0; nt < 4; ++nt)
            bfr[nt] = *(const bf16x8*)&lB[(no + nt * 16 + l15) * 32 + quad * 8];
#pragma unroll
        for (int mt = 0; mt < 4; ++mt)
#pragma unroll
            for (int nt = 0; nt < 4; ++nt)
                acc[mt][nt] = MFMA16(af[mt], bfr[nt], acc[mt][nt]);
    }

    // C layout: row m = quad*4+r, col n = lane&15
#pragma unroll
    for (int mt = 0; mt < 4; ++mt) {
        const int mg = m0 + mo + mt * 16 + quad * 4;
        const int t = mg >> 6, b0 = mg & 63;
#pragma unroll
        for (int nt = 0; nt < 4; ++nt) {
            const int n = n0 + no + nt * 16 + l15;
            const float bi = bih[n];
            ushort4 vv;
            vv.x = f2bf(acc[mt][nt][0] + bi);
            vv.y = f2bf(acc[mt][nt][1] + bi);
            vv.z = f2bf(acc[mt][nt][2] + bi);
            vv.w = f2bf(acc[mt][nt][3] + bi);
            *(ushort4*)&gx[((size_t)t * G3 + n) * 64 + b0] = vv;
        }
    }
}

// ---------------------------------------------------------------- scan ------
// 128 blocks x 512 thr = 4 batch groups x 32 col blocks. Tagged h words
// (u32 = bf16<<16 | step_tag): producers store with NO drain / NO flag.
// Consume-as-arrives: wave kq's MFMA slice s needs exactly producer block
// p = 8*kq+s's 32 cols, so each wave polls its own 512 B slice directly from
// global (2 x dwordx4 / lane), retries that slice only, and runs its 3 MFMAs
// as soon as it lands. No LDS h staging, no block-wide pull, one barrier per
// step (red double-buffered by parity). Slot-reuse safety: producing h_{t+2}
// follows sync(t+1), which requires every wave past its slice reads of t.
__global__ __launch_bounds__(512, 1)
void scan_kernel(const u16* __restrict__ whh, const float* __restrict__ bhh,
                 const u16* __restrict__ gx, u32* __restrict__ hball,
                 const float* __restrict__ wfc, float* __restrict__ out) {
    __shared__ __align__(16) float red[2][2][3][4][16 * 20]; // [par][nh][g][kq][m*20+n]

    const int bid = blockIdx.x;
    const int bg = bid >> 5;          // batch group 0..3 (rows 16bg..+16)
    const int cg = bid & 31;          // col group 0..31 (cols 32cg..+32)
    const int tid = threadIdx.x;
    const int w = tid >> 6;           // wave 0..7
    const int lane = tid & 63;
    const int kq = w & 3;             // K-quarter
    const int nh = w >> 2;            // col-half
    const int quad = lane >> 4, l15 = lane & 15;
    const int c0 = cg * 32;
    const bool isGate = (w == 3) || (w == 4);
    const int gnh = (w == 3) ? 0 : 1;

    // register-resident W: B-frag for col c0+nh*16+l15, gate g, k-chunk kq*8+s
    bf16x8 wf[3][8];
#pragma unroll
    for (int g = 0; g < 3; ++g) {
        const size_t rbase = (size_t)(g * 1024 + c0 + nh * 16 + l15) * 1024;
#pragma unroll
        for (int s = 0; s < 8; ++s)
            wf[g][s] = *(const bf16x8*)&whh[rbase + (kq * 8 + s) * 32 + quad * 8];
    }

    // gate-wave per-lane state: (b = bg*16+l15, j = c0+gnh*16+quad*4+jj)
    float bh[3][4];
    u16 gxv[3][4];
    float hO[4] = {0.f, 0.f, 0.f, 0.f};
    if (isGate) {
#pragma unroll
        for (int g = 0; g < 3; ++g)
#pragma unroll
            for (int jj = 0; jj < 4; ++jj) {
                const int jglob = c0 + gnh * 16 + quad * 4 + jj;
                bh[g][jj] = bhh[g * 1024 + jglob];
                gxv[g][jj] = gx[((size_t)g * 1024 + jglob) * 64 + bg * 16 + l15];
            }
    }

    u32* hb = hball + (size_t)bg * 32768;   // group base (2 slots x 16384 u32)
    // this lane's word base within a slot: row l15, cols kq*256 + s*32 + quad*8
    const int wbase = l15 * 1024 + kq * 256 + quad * 8;

    for (int t = 0; t < 512; ++t) {
        const u32* hs = hb + ((t & 1) << 14);
        const u32 tg = (u32)t;
        const int par = t & 1;

        f32x4 acc[3] = {};
#pragma unroll
        for (int s = 0; s < 8; ++s) {
            const u32* p0 = hs + wbase + s * 32;
            const u32* p1 = p0 + 4;
            u32x4 a0, a1;
            for (;;) {
                asm volatile(
                    "global_load_dwordx4 %0, %2, off sc0 sc1\n\t"
                    "global_load_dwordx4 %1, %3, off sc0 sc1\n\t"
                    "s_waitcnt vmcnt(0)"
                    : "=&v"(a0), "=&v"(a1)
                    : "v"(p0), "v"(p1)
                    : "memory");
                __builtin_amdgcn_sched_barrier(0);
                const u32 d = ((a0.x ^ tg) | (a0.y ^ tg) | (a0.z ^ tg) | (a0.w ^ tg) |
                               (a1.x ^ tg) | (a1.y ^ tg) | (a1.z ^ tg) | (a1.w ^ tg)) &
                              0xffffu;
                if (__all(d == 0)) break;
                __builtin_amdgcn_s_sleep(1);
            }
            // strip tags -> A-frag (8 bf16: cols quad*8+0..7 of row l15)
            union { u32 u[4]; bf16x8 v; } fr;
            fr.u[0] = (a0.x >> 16) | (a0.y & 0xffff0000u);
            fr.u[1] = (a0.z >> 16) | (a0.w & 0xffff0000u);
            fr.u[2] = (a1.x >> 16) | (a1.y & 0xffff0000u);
            fr.u[3] = (a1.z >> 16) | (a1.w & 0xffff0000u);
            acc[0] = MFMA16(fr.v, wf[0][s], acc[0]);
            acc[1] = MFMA16(fr.v, wf[1][s], acc[1]);
            acc[2] = MFMA16(fr.v, wf[2][s], acc[2]);
        }

        // transposed red store [m*20+n]: max 2-way conflict (free)
#pragma unroll
        for (int g = 0; g < 3; ++g)
#pragma unroll
            for (int r = 0; r < 4; ++r)
                red[par][nh][g][kq][(quad * 4 + r) * 20 + l15] = acc[g][r];
        __syncthreads();                      // red ready (parity-buffered)

        if (isGate) {
            f32x4 rr[3][4];
#pragma unroll
            for (int g = 0; g < 3; ++g)
#pragma unroll
                for (int k = 0; k < 4; ++k)
                    rr[g][k] = *(const f32x4*)&red[par][gnh][g][k][l15 * 20 + quad * 4];
            u32 wtag[4];
#pragma unroll
            for (int jj = 0; jj < 4; ++jj) {
                const float s0 = rr[0][0][jj] + rr[0][1][jj] + rr[0][2][jj] + rr[0][3][jj];
                const float s1 = rr[1][0][jj] + rr[1][1][jj] + rr[1][2][jj] + rr[1][3][jj];
                const float s2 = rr[2][0][jj] + rr[2][1][jj] + rr[2][2][jj] + rr[2][3][jj];
                const float rg = fast_sigmoid(bf2f(gxv[0][jj]) + s0 + bh[0][jj]);
                const float zg = fast_sigmoid(bf2f(gxv[1][jj]) + s1 + bh[1][jj]);
                const float ng = fast_tanh(bf2f(gxv[2][jj]) + rg * (s2 + bh[2][jj]));
                const float hv = (1.f - zg) * ng + zg * hO[jj];
                hO[jj] = hv;
                wtag[jj] = ((u32)f2bf(hv) << 16) | (u32)(t + 1);
            }
            if (t < 511) {
                // tagged self-validating stores: no drain, no flag
                u32* hn = hb + (((t + 1) & 1) << 14);
                const int widx = (l15 << 10) + c0 + gnh * 16 + (quad << 2);
                __hip_atomic_store((u64*)&hn[widx],
                                   (u64)wtag[0] | ((u64)wtag[1] << 32),
                                   __ATOMIC_RELAXED, __HIP_MEMORY_SCOPE_AGENT);
                __hip_atomic_store((u64*)&hn[widx + 2],
                                   (u64)wtag[2] | ((u64)wtag[3] << 32),
                                   __ATOMIC_RELAXED, __HIP_MEMORY_SCOPE_AGENT);
                // prefetch next step's gx (read-only, off critical path)
#pragma unroll
                for (int g = 0; g < 3; ++g)
#pragma unroll
                    for (int jj = 0; jj < 4; ++jj)
                        gxv[g][jj] = gx[((size_t)(t + 1) * G3 + g * 1024 + c0 +
                                         gnh * 16 + quad * 4 + jj) * 64 + bg * 16 + l15];
            }
        }
    }

    // FC head from gate-wave registers: hO[jj] = h_T(b=bg*16+l15, j)
    if (isGate) {
#pragma unroll
        for (int p = 0; p < 5; ++p) {
            float v = 0.f;
#pragma unroll
            for (int jj = 0; jj < 4; ++jj)
                v += hO[jj] * wfc[p * 1024 + c0 + gnh * 16 + quad * 4 + jj];
            v += __shfl_xor(v, 16);
            v += __shfl_xor(v, 32);
            if (quad == 0)
                atomicAdd(&out[(bg * 16 + l15) * 5 + p], v);
        }
    }
}

// --------------------------------------------------------------- launch -----
extern "C" void kernel_launch(void* const* d_in, const int* in_sizes, int n_in,
                              void* d_out, int out_size, void* d_ws, size_t ws_size,
                              hipStream_t stream) {
    const int*   x   = (const int*)d_in[0];
    const float* emb = (const float*)d_in[1];
    const float* wih = (const float*)d_in[2];
    const float* whh = (const float*)d_in[3];
    const float* bih = (const float*)d_in[4];
    const float* bhh = (const float*)d_in[5];
    const float* wfc = (const float*)d_in[6];
    const float* bfc = (const float*)d_in[7];
    float* out = (float*)d_out;

    char* ws = (char*)d_ws;
    u16*   gxw   = (u16*)(ws + OFF_GX);
    u16*   embbf = (u16*)(ws + OFF_EMB);
    u16*   wihbf = (u16*)(ws + OFF_WIH);
    u16*   whhbf = (u16*)(ws + OFF_WHH);
    u32*   h32   = (u32*)(ws + OFF_HBUF);

    prep_kernel<<<8192, 256, 0, stream>>>(x, emb, wih, whh, bfc, embbf, wihbf,
                                          whhbf, h32, out);

    gx_gemm<<<dim3(256, 24), 256, 0, stream>>>(embbf, wihbf, bih, gxw);

    scan_kernel<<<128, 512, 0, stream>>>(whhbf, bhh, gxw, h32, wfc, out);
}

// Round 4
// 2422.966 us; speedup vs baseline: 1.7786x; 1.7786x over previous
//
#include <hip/hip_runtime.h>
#include <hip/hip_bf16.h>

typedef unsigned short u16;
typedef unsigned int u32;
typedef unsigned long long u64;
typedef __attribute__((ext_vector_type(8))) short bf16x8;   // 8 bf16 in 4 VGPRs
typedef __attribute__((ext_vector_type(4))) float f32x4;    // MFMA acc
typedef __attribute__((ext_vector_type(4))) unsigned int u32x4;

#define MFMA16(a, b, c) __builtin_amdgcn_mfma_f32_16x16x32_bf16((a), (b), (c), 0, 0, 0)

static constexpr int Ee = 300, EP = 320, Hh = 1024, G3 = 3072;
static constexpr int Bb = 64, Tt = 512;

// workspace layout (bytes)
static constexpr long OFF_GX   = 0L;                      // [512][3072][64] bf16 = 201326592
static constexpr long OFF_EMB  = 201326592L;              // [32768][320] bf16   = 20971520
static constexpr long OFF_WIH  = 222298112L;              // [3072][320] bf16    = 1966080
static constexpr long OFF_WHH  = 224264192L;              // [3072][1024] bf16   = 6291456
static constexpr long OFF_HBUF = 230555648L;              // 4 grp x 2 slot x [16][1024] u32 tagged
static constexpr long OFF_FLAG = 231079936L;              // 4 grp x 64 flags x 64B

__device__ __forceinline__ u16 f2bf(float f) {
    union { float f; unsigned u; } v; v.f = f;
    unsigned u = v.u;
    return (u16)((u + 0x7fffu + ((u >> 16) & 1u)) >> 16);   // RNE
}
__device__ __forceinline__ float bf2f(u16 u) {
    union { unsigned u; float f; } v; v.u = ((unsigned)u) << 16;
    return v.f;
}
__device__ __forceinline__ float fast_sigmoid(float x) {
    return 1.f / (1.f + __expf(-x));
}
__device__ __forceinline__ float fast_tanh(float x) {
    float ax = fabsf(x);
    float e = __expf(-2.f * ax);
    float t = (1.f - e) / (1.f + e);
    return copysignf(t, x);
}

// barrier that orders LDS only — does NOT drain vmcnt (unlike __syncthreads,
// which emits s_waitcnt vmcnt(0) before s_barrier and would serialize our
// in-flight prefetches / store-acks into every step).
#define BAR_LDS()                                             \
    do {                                                      \
        asm volatile("s_waitcnt lgkmcnt(0)" ::: "memory");    \
        __builtin_amdgcn_s_barrier();                         \
    } while (0)

// ---------------------------------------------------------------- prep ------
static constexpr long R0 = (long)Bb * Tt * EP;   // emb gather (bf16, padded)
static constexpr long R1 = (long)G3 * EP;        // W_ih -> bf16 padded
static constexpr long R2 = (long)G3 * Hh;        // W_hh -> bf16
static constexpr long R3 = 131072;               // tagged h words: slot0 = h0|tag0, slot1 = sentinel
static constexpr long R4 = 4096;                 // flags = 0
static constexpr long R5 = 320;                  // out = bias (d_out is poisoned!)

__global__ void prep_kernel(const int* __restrict__ x, const float* __restrict__ emb,
                            const float* __restrict__ wih, const float* __restrict__ whh,
                            const float* __restrict__ bfc,
                            u16* __restrict__ emb_bf, u16* __restrict__ wih_bf,
                            u16* __restrict__ whh_bf, u32* __restrict__ h32,
                            int* __restrict__ flags, float* __restrict__ out) {
    const long total = R0 + R1 + R2 + R3 + R4 + R5;
    for (long i = (long)blockIdx.x * blockDim.x + threadIdx.x; i < total;
         i += (long)gridDim.x * blockDim.x) {
        if (i < R0) {
            const int m = (int)(i / EP), k = (int)(i % EP);
            const int b = m & 63, t = m >> 6;
            u16 v = 0;
            if (k < Ee) {
                const int xi = x[b * Tt + t];
                v = f2bf(emb[(size_t)xi * Ee + k]);
            }
            emb_bf[i] = v;
        } else if (i < R0 + R1) {
            const long j = i - R0;
            const int k = (int)(j % EP);
            const int n = (int)(j / EP);
            wih_bf[j] = (k < Ee) ? f2bf(wih[(size_t)n * Ee + k]) : (u16)0;
        } else if (i < R0 + R1 + R2) {
            const long j = i - R0 - R1;
            whh_bf[j] = f2bf(whh[j]);
        } else if (i < R0 + R1 + R2 + R3) {
            const long j = i - R0 - R1 - R2;
            // per group: slot0 = payload 0 / tag 0 == h_0; slot1 = sentinel
            h32[j] = ((j >> 14) & 1) ? 0xFFFFu : 0u;
        } else if (i < R0 + R1 + R2 + R3 + R4) {
            flags[i - R0 - R1 - R2 - R3] = 0;
        } else {
            const long j = i - R0 - R1 - R2 - R3 - R4;
            out[j] = bfc[j % 5];
        }
    }
}

// ------------------------------------------------------------- gx GEMM ------
// gx[t][n][b] = sum_k emb_bf[m=t*64+b][k] * wih_bf[n][k] + b_ih[n], bf16 out.
__global__ __launch_bounds__(256, 2)
void gx_gemm(const u16* __restrict__ A, const u16* __restrict__ Bm,
             const float* __restrict__ bih, u16* __restrict__ gx) {
    __shared__ __align__(16) u16 lA[128 * 32];
    __shared__ __align__(16) u16 lB[128 * 32];
    const int tid = threadIdx.x;
    const int lane = tid & 63;
    const int wv = tid >> 6;
    const int quad = lane >> 4, l15 = lane & 15;
    const int m0 = blockIdx.x * 128;
    const int n0 = blockIdx.y * 128;
    const int mo = (wv & 1) * 64, no = (wv >> 1) * 64;
    const int srow = tid >> 2;
    const int sseg = tid & 3;

    f32x4 acc[4][4] = {};

    for (int s = 0; s < 10; ++s) {
        const int k0 = s * 32;
        __syncthreads();
#pragma unroll
        for (int p = 0; p < 2; ++p) {
            const u16* ga = A + (size_t)(m0 + p * 64 + srow) * EP + k0 + sseg * 8;
            u16* la = &lA[p * 2048 + wv * 512];
            __builtin_amdgcn_global_load_lds(
                (const __attribute__((address_space(1))) void*)ga,
                (__attribute__((address_space(3))) void*)la, 16, 0, 0);
            const u16* gb = Bm + (size_t)(n0 + p * 64 + srow) * EP + k0 + sseg * 8;
            u16* lb = &lB[p * 2048 + wv * 512];
            __builtin_amdgcn_global_load_lds(
                (const __attribute__((address_space(1))) void*)gb,
                (__attribute__((address_space(3))) void*)lb, 16, 0, 0);
        }
        __syncthreads();

        bf16x8 af[4], bfr[4];
#pragma unroll
        for (int mt = 0; mt < 4; ++mt)
            af[mt] = *(const bf16x8*)&lA[(mo + mt * 16 + l15) * 32 + quad * 8];
#pragma unroll
        for (int nt = 0; nt < 4; ++nt)
            bfr[nt] = *(const bf16x8*)&lB[(no + nt * 16 + l15) * 32 + quad * 8];
#pragma unroll
        for (int mt = 0; mt < 4; ++mt)
#pragma unroll
            for (int nt = 0; nt < 4; ++nt)
                acc[mt][nt] = MFMA16(af[mt], bfr[nt], acc[mt][nt]);
    }

    // C layout: row m = quad*4+r, col n = lane&15
#pragma unroll
    for (int mt = 0; mt < 4; ++mt) {
        const int mg = m0 + mo + mt * 16 + quad * 4;
        const int t = mg >> 6, b0 = mg & 63;
#pragma unroll
        for (int nt = 0; nt < 4; ++nt) {
            const int n = n0 + no + nt * 16 + l15;
            const float bi = bih[n];
            ushort4 vv;
            vv.x = f2bf(acc[mt][nt][0] + bi);
            vv.y = f2bf(acc[mt][nt][1] + bi);
            vv.z = f2bf(acc[mt][nt][2] + bi);
            vv.w = f2bf(acc[mt][nt][3] + bi);
            *(ushort4*)&gx[((size_t)t * G3 + n) * 64 + b0] = vv;
        }
    }
}

// ---------------------------------------------------------------- scan ------
// 128 blocks x 512 thr = 4 batch groups x 32 col blocks.
// Protocol: h words are tagged (u32 = bf16<<16 | step). Producers store data
// then flag with NO drain (tags make data self-validating; the flag only
// makes the spin cheap: 256 B/wave/iter vs 64 KB). Consumers: flag spin ->
// one-shot 64KB block-wide pull with tag verify -> rare partial retry.
// Raw lgkm-only barriers (no vmcnt drain). Gate waves prefetch gx(t+1) as
// inline-asm loads during step t's pull; positional s_waitcnt vmcnt(12)
// (8 pull + 12 gx outstanding) waits only for the pull. The next step's
// poll vmcnt(0) drains the gx loads a full step after issue (free); a
// data-dependence pin keeps gx uses after that drain (rule #18).
// Slot-reuse safety: producing h_{t+2} (slot t&1) requires this block's
// sync(t+1), which requires detecting all flags>=t+1, which requires every
// block's gates past sync2(t), which (barrier) requires all that block's
// waves' pulls of step t complete. Exact-tag spin cannot deadlock.
__global__ __launch_bounds__(512, 2)
void scan_kernel(const u16* __restrict__ whh, const float* __restrict__ bhh,
                 const u16* __restrict__ gx, u32* __restrict__ hball,
                 const float* __restrict__ wfc, float* __restrict__ out,
                 int* __restrict__ flags) {
    __shared__ __align__(16) u16 lh[16 * 1032];           // staged h (row 258 u64)
    __shared__ __align__(16) float red[2][3][4][16 * 20]; // [nh][g][kq][m*20+n]

    const int bid = blockIdx.x;
    const int bg = bid >> 5;          // batch group 0..3 (rows 16bg..+16)
    const int cg = bid & 31;          // col group 0..31 (cols 32cg..+32)
    const int tid = threadIdx.x;
    const int w = tid >> 6;           // wave 0..7
    const int lane = tid & 63;
    const int kq = w & 3;             // K-quarter
    const int nh = w >> 2;            // col-half
    const int quad = lane >> 4, l15 = lane & 15;
    const int c0 = cg * 32;
    const bool isGate = (w == 3) || (w == 4);
    const int gnh = (w == 3) ? 0 : 1;
    const int jbase = c0 + gnh * 16 + quad * 4;

    // register-resident W: B-frag for col c0+nh*16+l15, gate g, k-chunk kq*8+s
    bf16x8 wf[3][8];
#pragma unroll
    for (int g = 0; g < 3; ++g) {
        const size_t rbase = (size_t)(g * 1024 + c0 + nh * 16 + l15) * 1024;
#pragma unroll
        for (int s = 0; s < 8; ++s)
            wf[g][s] = *(const bf16x8*)&whh[rbase + (kq * 8 + s) * 32 + quad * 8];
    }

    // gate-wave per-lane state: (b = bg*16+l15, j = jbase+jj)
    float bh[3][4];
    u32 gxA[12], gxB[12];             // zext bf16 bits; double-buffered sets
    float hO[4] = {0.f, 0.f, 0.f, 0.f};
    if (isGate) {
#pragma unroll
        for (int g = 0; g < 3; ++g)
#pragma unroll
            for (int jj = 0; jj < 4; ++jj) {
                bh[g][jj] = bhh[g * 1024 + jbase + jj];
                gxA[g * 4 + jj] =
                    (u32)gx[((size_t)(g * 1024 + jbase + jj)) * 64 + bg * 16 + l15];
            }
    }
    // gx byte-pointers for t+1 = 1 (advanced each body call)
    const long GSTEP = (long)G3 * 64 * 2;
    const char* gp0 = (const char*)gx +
                      (((size_t)1 * G3 + 0 * 1024 + jbase) * 64 + bg * 16 + l15) * 2;
    const char* gp1 = gp0 + (size_t)1024 * 64 * 2;
    const char* gp2 = gp1 + (size_t)1024 * 64 * 2;

    u32* hb = hball + (size_t)bg * 32768;        // group base (2 slots x 16384 u32)
    int* gflag = &flags[(bg * 64 + lane) * 16];  // this lane's polled flag
    int* myflag = &flags[(bg * 64 + cg * 2 + gnh) * 16];
    const int t4 = tid << 2;                     // word offset of this thread's dwordx4
    const int srow0 = tid >> 8;
    const int sc4 = tid & 255;
    u64* lhq = (u64*)lh;

    auto body = [&](const int t, u32 (&gxCur)[12], u32 (&gxNxt)[12]) {
        const u32* hs = hb + ((t & 1) << 14);
        const u32 tg = (u32)t;

        // ---- cheap flag spin (1 dword/lane) ----
        int v = __hip_atomic_load(gflag, __ATOMIC_RELAXED, __HIP_MEMORY_SCOPE_AGENT);
        bool done = (v >= t);
        while (!__all(done)) {
            __builtin_amdgcn_s_sleep(1);
            if (!done) {
                v = __hip_atomic_load(gflag, __ATOMIC_RELAXED, __HIP_MEMORY_SCOPE_AGENT);
                done = (v >= t);
            }
        }
        // pin: gxCur (issued a full step ago) became valid at the poll's
        // vmcnt(0); the dep on v keeps this (and thus gxCur uses) after it.
        if (isGate)
            asm volatile("" : "+v"(gxCur[0]), "+v"(gxCur[1]), "+v"(gxCur[2]),
                              "+v"(gxCur[3]), "+v"(gxCur[4]), "+v"(gxCur[5]),
                              "+v"(gxCur[6]), "+v"(gxCur[7]), "+v"(gxCur[8]),
                              "+v"(gxCur[9]), "+v"(gxCur[10]), "+v"(gxCur[11])
                            : "v"(v));

        // ---- one-shot pull (block-wide coverage) + gate gx(t+1) prefetch ----
        const u32* p0 = hs + t4;
        const u32* p1 = hs + 2048 + t4;
        const u32* p2 = hs + 4096 + t4;
        const u32* p3 = hs + 6144 + t4;
        const u32* p4 = hs + 8192 + t4;
        const u32* p5 = hs + 10240 + t4;
        const u32* p6 = hs + 12288 + t4;
        const u32* p7 = hs + 14336 + t4;
        u32x4 q0, q1, q2, q3, q4, q5, q6, q7;
        asm volatile(
            "global_load_dwordx4 %0, %8, off sc0 sc1\n\t"
            "global_load_dwordx4 %1, %9, off sc0 sc1\n\t"
            "global_load_dwordx4 %2, %10, off sc0 sc1\n\t"
            "global_load_dwordx4 %3, %11, off sc0 sc1\n\t"
            "global_load_dwordx4 %4, %12, off sc0 sc1\n\t"
            "global_load_dwordx4 %5, %13, off sc0 sc1\n\t"
            "global_load_dwordx4 %6, %14, off sc0 sc1\n\t"
            "global_load_dwordx4 %7, %15, off sc0 sc1"
            : "=&v"(q0), "=&v"(q1), "=&v"(q2), "=&v"(q3),
              "=&v"(q4), "=&v"(q5), "=&v"(q6), "=&v"(q7)
            : "v"(p0), "v"(p1), "v"(p2), "v"(p3),
              "v"(p4), "v"(p5), "v"(p6), "v"(p7)
            : "memory");
        if (isGate && t < 511) {
            asm volatile(
                "global_load_ushort %0, %4, off\n\t"
                "global_load_ushort %1, %4, off offset:128\n\t"
                "global_load_ushort %2, %4, off offset:256\n\t"
                "global_load_ushort %3, %4, off offset:384"
                : "=&v"(gxNxt[0]), "=&v"(gxNxt[1]), "=&v"(gxNxt[2]), "=&v"(gxNxt[3])
                : "v"(gp0) : "memory");
            asm volatile(
                "global_load_ushort %0, %4, off\n\t"
                "global_load_ushort %1, %4, off offset:128\n\t"
                "global_load_ushort %2, %4, off offset:256\n\t"
                "global_load_ushort %3, %4, off offset:384"
                : "=&v"(gxNxt[4]), "=&v"(gxNxt[5]), "=&v"(gxNxt[6]), "=&v"(gxNxt[7])
                : "v"(gp1) : "memory");
            asm volatile(
                "global_load_ushort %0, %4, off\n\t"
                "global_load_ushort %1, %4, off offset:128\n\t"
                "global_load_ushort %2, %4, off offset:256\n\t"
                "global_load_ushort %3, %4, off offset:384"
                : "=&v"(gxNxt[8]), "=&v"(gxNxt[9]), "=&v"(gxNxt[10]), "=&v"(gxNxt[11])
                : "v"(gp2) : "memory");
            // positional: 8 pull (older) + 12 gx (newer); vmcnt(12) retires
            // exactly the 8 pulls, gx stays in flight across the barriers.
            asm volatile("s_waitcnt vmcnt(12)" ::: "memory");
        } else {
            asm volatile("s_waitcnt vmcnt(0)" ::: "memory");
        }
        gp0 += GSTEP; gp1 += GSTEP; gp2 += GSTEP;
        __builtin_amdgcn_sched_barrier(0);

        // ---- tag verify; rare partial retry (flag can overtake data) ----
        u32 pend = 0;
#define TCHK(bit, qq)                                                         \
        {                                                                     \
            const u32 d = ((qq.x ^ tg) | (qq.y ^ tg) |                        \
                           (qq.z ^ tg) | (qq.w ^ tg)) & 0xffffu;              \
            if (!__all(d == 0)) pend |= (bit);                                \
        }
        TCHK(0x01u, q0) TCHK(0x02u, q1) TCHK(0x04u, q2) TCHK(0x08u, q3)
        TCHK(0x10u, q4) TCHK(0x20u, q5) TCHK(0x40u, q6) TCHK(0x80u, q7)
        while (pend) {
            __builtin_amdgcn_s_sleep(1);
            if (pend & 0x01u) asm volatile("global_load_dwordx4 %0, %1, off sc0 sc1" : "=&v"(q0) : "v"(p0) : "memory");
            if (pend & 0x02u) asm volatile("global_load_dwordx4 %0, %1, off sc0 sc1" : "=&v"(q1) : "v"(p1) : "memory");
            if (pend & 0x04u) asm volatile("global_load_dwordx4 %0, %1, off sc0 sc1" : "=&v"(q2) : "v"(p2) : "memory");
            if (pend & 0x08u) asm volatile("global_load_dwordx4 %0, %1, off sc0 sc1" : "=&v"(q3) : "v"(p3) : "memory");
            if (pend & 0x10u) asm volatile("global_load_dwordx4 %0, %1, off sc0 sc1" : "=&v"(q4) : "v"(p4) : "memory");
            if (pend & 0x20u) asm volatile("global_load_dwordx4 %0, %1, off sc0 sc1" : "=&v"(q5) : "v"(p5) : "memory");
            if (pend & 0x40u) asm volatile("global_load_dwordx4 %0, %1, off sc0 sc1" : "=&v"(q6) : "v"(p6) : "memory");
            if (pend & 0x80u) asm volatile("global_load_dwordx4 %0, %1, off sc0 sc1" : "=&v"(q7) : "v"(p7) : "memory");
            asm volatile("s_waitcnt vmcnt(0)" ::: "memory");   // rare path
            __builtin_amdgcn_sched_barrier(0);
            u32 np = 0;
#define RCHK(bit, qq)                                                         \
            if (pend & (bit)) {                                               \
                const u32 d = ((qq.x ^ tg) | (qq.y ^ tg) |                    \
                               (qq.z ^ tg) | (qq.w ^ tg)) & 0xffffu;          \
                if (!__all(d == 0)) np |= (bit);                              \
            }
            RCHK(0x01u, q0) RCHK(0x02u, q1) RCHK(0x04u, q2) RCHK(0x08u, q3)
            RCHK(0x10u, q4) RCHK(0x20u, q5) RCHK(0x40u, q6) RCHK(0x80u, q7)
#undef RCHK
            pend = np;
        }
#undef TCHK

        // ---- strip tags, pack bf16 pairs -> LDS ----
#define UNPK(rr, qq)                                                          \
        {                                                                     \
            const int row = (rr) * 2 + srow0;                                 \
            const u32 lo = (qq.x >> 16) | (qq.y & 0xffff0000u);               \
            const u32 hi = (qq.z >> 16) | (qq.w & 0xffff0000u);               \
            lhq[row * 258 + sc4] = (u64)lo | ((u64)hi << 32);                 \
        }
        UNPK(0, q0) UNPK(1, q1) UNPK(2, q2) UNPK(3, q3)
        UNPK(4, q4) UNPK(5, q5) UNPK(6, q6) UNPK(7, q7)
#undef UNPK
        BAR_LDS();                             // sync1: lh ready (LDS only)

        // MFMA over this wave's K-quarter, 3 gates
        bf16x8 af[8];
#pragma unroll
        for (int s = 0; s < 8; ++s)
            af[s] = *(const bf16x8*)&lh[l15 * 1032 + kq * 256 + s * 32 + quad * 8];
        f32x4 acc[3] = {};
#pragma unroll
        for (int s = 0; s < 8; ++s) {
            acc[0] = MFMA16(af[s], wf[0][s], acc[0]);
            acc[1] = MFMA16(af[s], wf[1][s], acc[1]);
            acc[2] = MFMA16(af[s], wf[2][s], acc[2]);
        }
        // transposed red store [m*20+n]: max 2-way conflict (free)
#pragma unroll
        for (int g = 0; g < 3; ++g)
#pragma unroll
            for (int r = 0; r < 4; ++r)
                red[nh][g][kq][(quad * 4 + r) * 20 + l15] = acc[g][r];
        BAR_LDS();                             // sync2: red ready (LDS only)

        if (isGate) {
            f32x4 rr[3][4];
#pragma unroll
            for (int g = 0; g < 3; ++g)
#pragma unroll
                for (int k = 0; k < 4; ++k)
                    rr[g][k] = *(const f32x4*)&red[gnh][g][k][l15 * 20 + quad * 4];
            u32 wtag[4];
#pragma unroll
            for (int jj = 0; jj < 4; ++jj) {
                const float s0 = rr[0][0][jj] + rr[0][1][jj] + rr[0][2][jj] + rr[0][3][jj];
                const float s1 = rr[1][0][jj] + rr[1][1][jj] + rr[1][2][jj] + rr[1][3][jj];
                const float s2 = rr[2][0][jj] + rr[2][1][jj] + rr[2][2][jj] + rr[2][3][jj];
                const float rg = fast_sigmoid(bf2f((u16)gxCur[0 * 4 + jj]) + s0 + bh[0][jj]);
                const float zg = fast_sigmoid(bf2f((u16)gxCur[1 * 4 + jj]) + s1 + bh[1][jj]);
                const float ng = fast_tanh(bf2f((u16)gxCur[2 * 4 + jj]) + rg * (s2 + bh[2][jj]));
                const float hv = (1.f - zg) * ng + zg * hO[jj];
                hO[jj] = hv;
                wtag[jj] = ((u32)f2bf(hv) << 16) | (u32)(t + 1);
            }
            if (t < 511) {
                // tagged self-validating stores: NO drain; flag right after.
                u32* hn = hb + (((t + 1) & 1) << 14);
                const int widx = (l15 << 10) + jbase;
                const u64 d0 = (u64)wtag[0] | ((u64)wtag[1] << 32);
                const u64 d1 = (u64)wtag[2] | ((u64)wtag[3] << 32);
                asm volatile("global_store_dwordx2 %0, %1, off sc0 sc1"
                             :: "v"((u64*)&hn[widx]), "v"(d0) : "memory");
                asm volatile("global_store_dwordx2 %0, %1, off sc0 sc1"
                             :: "v"((u64*)&hn[widx + 2]), "v"(d1) : "memory");
                if (lane == 0)
                    __hip_atomic_store(myflag, t + 1, __ATOMIC_RELAXED,
                                       __HIP_MEMORY_SCOPE_AGENT);
            }
        }
    };

    for (int t = 0; t < 512; t += 2) {
        body(t, gxA, gxB);
        body(t + 1, gxB, gxA);
    }

    // FC head from gate-wave registers: hO[jj] = h_T(b=bg*16+l15, j)
    if (isGate) {
#pragma unroll
        for (int p = 0; p < 5; ++p) {
            float v = 0.f;
#pragma unroll
            for (int jj = 0; jj < 4; ++jj)
                v += hO[jj] * wfc[p * 1024 + jbase + jj];
            v += __shfl_xor(v, 16);
            v += __shfl_xor(v, 32);
            if (quad == 0)
                atomicAdd(&out[(bg * 16 + l15) * 5 + p], v);
        }
    }
}

// --------------------------------------------------------------- launch -----
extern "C" void kernel_launch(void* const* d_in, const int* in_sizes, int n_in,
                              void* d_out, int out_size, void* d_ws, size_t ws_size,
                              hipStream_t stream) {
    const int*   x   = (const int*)d_in[0];
    const float* emb = (const float*)d_in[1];
    const float* wih = (const float*)d_in[2];
    const float* whh = (const float*)d_in[3];
    const float* bih = (const float*)d_in[4];
    const float* bhh = (const float*)d_in[5];
    const float* wfc = (const float*)d_in[6];
    const float* bfc = (const float*)d_in[7];
    float* out = (float*)d_out;

    char* ws = (char*)d_ws;
    u16*   gxw   = (u16*)(ws + OFF_GX);
    u16*   embbf = (u16*)(ws + OFF_EMB);
    u16*   wihbf = (u16*)(ws + OFF_WIH);
    u16*   whhbf = (u16*)(ws + OFF_WHH);
    u32*   h32   = (u32*)(ws + OFF_HBUF);
    int*   flags = (int*)(ws + OFF_FLAG);

    prep_kernel<<<8192, 256, 0, stream>>>(x, emb, wih, whh, bfc, embbf, wihbf,
                                          whhbf, h32, flags, out);

    gx_gemm<<<dim3(256, 24), 256, 0, stream>>>(embbf, wihbf, bih, gxw);

    scan_kernel<<<128, 512, 0, stream>>>(whhbf, bhh, gxw, h32, wfc, out, flags);
}